// Round 10
// baseline (173.417 us; speedup 1.0000x reference)
//
#include <hip/hip_runtime.h>
#include <math.h>

// Shapes (fixed by the problem)
#define Hn 8
#define Sn 1024
#define Dn 64
#define KG 10

// Bias tables: dist in [0,10), energy in [0,5)
#define TN 2048
#define RD 10.25f
#define RE 5.125f

// k-split: grid (Sn/64, Hn, KS) = 512 blocks -> 2 blocks/CU at 80 KB LDS
#define KS 4

typedef __attribute__((ext_vector_type(8))) short bf16x8;
typedef __attribute__((ext_vector_type(4))) float f32x4;
typedef unsigned short u16;
typedef unsigned int u32;

__device__ inline float bf2f(u16 u) {
    union { u32 i; float f; } v;
    v.i = ((u32)u) << 16;
    return v.f;
}

__device__ inline u16 f2bf(float f) {
    union { float f; u32 i; } v;
    v.f = f;
    u32 i = v.i;
    return (u16)((i + 0x7FFFu + ((i >> 16) & 1u)) >> 16);   // RNE
}

// Fire-and-forget global->LDS DMA, 16 B per lane (R7/R8-proven mechanism:
// no VGPR destination -> RA cannot re-serialize; compiler never defeats it).
// LDS dest = wave-uniform base + lane*16; readback at lane*16 is identity.
__device__ inline void stage16(const void* g, void* l) {
    __builtin_amdgcn_global_load_lds(
        (const __attribute__((address_space(1))) unsigned int*)g,
        (__attribute__((address_space(3))) unsigned int*)l,
        16, 0, 0);
}

// ---------------------------------------------------------------------------
// RBF (10 gaussians) -> 10x10 MLP (exact gelu) -> scalar, all f32.
// ---------------------------------------------------------------------------
__device__ float bias_eval(float x,
                           const float* __restrict__ mu, const float* __restrict__ sg,
                           const float* __restrict__ bb,
                           const float* __restrict__ W1, const float* __restrict__ b1,
                           const float* __restrict__ W2, const float* __restrict__ b2) {
    const float inv_s2pi = 0.39894228040143267794f;
    float psi[KG];
#pragma unroll
    for (int k = 0; k < KG; k++) {
        float s = sg[k];
        float z = (x + bb[k] - mu[k]) / s;
        psi[k] = __expf(-0.5f * z * z) * (inv_s2pi / s);
    }
    float out = b2[0];
#pragma unroll
    for (int l = 0; l < KG; l++) {
        float a = b1[l];
#pragma unroll
        for (int k = 0; k < KG; k++) a += psi[k] * W1[l * KG + k];
        float g = 0.5f * a * (1.0f + erff(a * 0.70710678118654752440f));
        out += g * W2[l];
    }
    return out;
}

// ---------------------------------------------------------------------------
// Fused prepass (unchanged):
//  ids [0, 2*TN)                 : bias interp tables (bf16 value | bf16 delta)
//  ids [2*TN, 2*TN+262144)       : Q,K f32 -> bf16 (float4 granularity)
//  ids [2*TN+262144, +524288)    : V -> bf16, transposed [h][d][s'] with the
//                                  k-permutation matching the P register order
// ---------------------------------------------------------------------------
#define QK4 262144              // (2*Hn*Sn*Dn)/4
#define VTN 524288              // Hn*Sn*Dn

__global__ __launch_bounds__(256) void prep_kernel(
    const float* __restrict__ Q, const float* __restrict__ K, const float* __restrict__ V,
    const float* __restrict__ muD, const float* __restrict__ sgD, const float* __restrict__ bD,
    const float* __restrict__ muE, const float* __restrict__ sgE, const float* __restrict__ bE,
    const float* __restrict__ W1, const float* __restrict__ b1,
    const float* __restrict__ W2, const float* __restrict__ b2,
    u32* __restrict__ tab, u16* __restrict__ Qb, u16* __restrict__ Kb, u16* __restrict__ VTi)
{
    int id = blockIdx.x * 256 + threadIdx.x;
    if (id < 2 * TN) {
        int which = (id >= TN);
        int idx = id & (TN - 1);
        float h = (which ? RE : RD) / (float)TN;
        float x0 = idx * h;
        float v0, v1;
        if (which) {
            v0 = bias_eval(x0,     muE, sgE, bE, W1, b1, W2, b2);
            v1 = bias_eval(x0 + h, muE, sgE, bE, W1, b1, W2, b2);
        } else {
            v0 = bias_eval(x0,     muD, sgD, bD, W1, b1, W2, b2);
            v1 = bias_eval(x0 + h, muD, sgD, bD, W1, b1, W2, b2);
        }
        tab[id] = (u32)f2bf(v0) | ((u32)f2bf(v1 - v0) << 16);
    } else if (id < 2 * TN + QK4) {
        int i = id - 2 * TN;
        int arr = i >> 17;          // 0 = Q, 1 = K
        i &= (1 << 17) - 1;
        float4 v = ((const float4*)(arr ? K : Q))[i];
        ushort4 o;
        o.x = f2bf(v.x); o.y = f2bf(v.y); o.z = f2bf(v.z); o.w = f2bf(v.w);
        ((ushort4*)(arr ? Kb : Qb))[i] = o;
    } else if (id < 2 * TN + QK4 + VTN) {
        int g = id - (2 * TN + QK4);
        int h = g >> 16;
        int d = (g >> 10) & 63;
        int s = g & 1023;
        int t = s >> 5, q = (s >> 3) & 3, j = s & 7;
        int src_s = (t << 5) + (q << 2) + (j & 3) + ((j >> 2) << 4);
        VTi[g] = f2bf(V[(((size_t)h << 10) + src_s) * Dn + d]);
    }
}

__device__ inline float lerp_tab(const u32* __restrict__ st, float x, float invh) {
    float tf = x * invh;
    int i = (int)tf;
    i = max(0, min(i, TN - 1));
    float fr = tf - (float)i;
    u32 p = st[i];
    return fmaf(bf2f((u16)(p >> 16)), fr, bf2f((u16)p));
}

// ---------------------------------------------------------------------------
// Fused flash attention with SHARED K/V staging.
// R8 diagnosis: kernel is VMEM-pipe-throughput-bound at ~5.3 TB/s moving
// 229 MB, of which 131 MB was K/V re-staged per q-tile block. Here a block
// covers 64 q-rows (4 waves x 16-row q-tiles) sweeping the SAME k-tiles, so
// K/V is staged ONCE per block into shared LDS: waves 0-1 stage K, waves 2-3
// stage V, every wave stages its own D/E/M rows (8 DMAs/wave/tile uniform).
// Traffic: 96 MB D/E/M (irreducible) + 33 MB K/V + partials ~= 146 MB.
// Double-buffered 32 KB tile buffers; ONE __syncthreads per tile provides
// both cross-wave data visibility (implicit vmcnt(0)+barrier) and clobber
// ordering. Each wave covers the block's full k-range -> per-wave partial
// (m,l,U); combine merges the KS=4 partials per q-row.
// LDS: 16 KB table + 2x32 KB = 80 KB -> 2 blocks/CU.
// ---------------------------------------------------------------------------
#define BUFSZ 32768

__global__ __launch_bounds__(256) void attn_kernel(
    const u16* __restrict__ Qb, const u16* __restrict__ Kb, const u16* __restrict__ VTi,
    const float* __restrict__ Dm, const float* __restrict__ Em, const int* __restrict__ Mk,
    const u32* __restrict__ gtab,
    float* __restrict__ Up, float* __restrict__ Mp, float* __restrict__ Lp)
{
    __shared__ __align__(16) u32 sTab[2 * TN];      // 16 KB
    __shared__ __align__(16) char sBuf[2 * BUFSZ];  // 64 KB double buffer

    const int tid = threadIdx.x;
    {   // stage tables: 1024 uint4 over 256 threads
        const uint4* g4 = (const uint4*)gtab;
        uint4* s4 = (uint4*)sTab;
#pragma unroll
        for (int i = 0; i < 4; i++) s4[tid + 256 * i] = g4[tid + 256 * i];
    }

    const int h    = blockIdx.y;
    const int qb   = blockIdx.x;        // 64-row q-panel
    const int ks   = blockIdx.z;        // k-range [ks*256, ks*256+256)
    const int wave = tid >> 6;
    const int lane = tid & 63;
    const int quad = lane >> 4;
    const int l16  = lane & 15;
    const int q0   = qb * 64 + wave * 16;   // this wave's q-tile
    const int kbase = ks * 256;

    const u16* Qh = Qb  + (size_t)h * Sn * Dn;
    const u16* Kh = Kb  + (size_t)h * Sn * Dn;
    const u16* Vh = VTi + (size_t)h * Dn * Sn;
    const float* Dh = Dm + (size_t)h * Sn * Sn + (size_t)(q0 + l16) * Sn;
    const float* Eh = Em + (size_t)h * Sn * Sn + (size_t)(q0 + l16) * Sn;
    const int*   Mh = Mk + (size_t)h * Sn * Sn + (size_t)(q0 + l16) * Sn;
    const float invhD = (float)TN / RD;
    const float invhE = (float)TN / RE;
    const float scale = 0.08838834764831845f;       // 1/sqrt(2*64)

    // Persistent Q B-fragments for this wave's q-tile
    const bf16x8 bQ0 = *(const bf16x8*)(Qh + (q0 + l16) * Dn + quad * 8);
    const bf16x8 bQ1 = *(const bf16x8*)(Qh + (q0 + l16) * Dn + 32 + quad * 8);

    // One tile buffer layout (32 KB):
    //  [0,4K)   K chunks 0-3 (staged by waves 0-1)
    //  [4K,8K)  V chunks 0-3 (staged by waves 2-3)
    //  [8K,32K) D/E/M: wave w region at 8K + w*6K (6 chunks of 1 KB)
#define STAGE(bufp, tt) do {                                                   \
        const int k0_ = kbase + (tt) * 32;                                     \
        char* b_ = (bufp);                                                     \
        if (wave < 2) {                                                        \
            const u16* kr_ = Kh + (size_t)(k0_ + l16 + wave * 16) * Dn + quad * 8; \
            stage16(kr_,      b_ + wave * 2048);                               \
            stage16(kr_ + 32, b_ + wave * 2048 + 1024);                        \
        } else {                                                               \
            const int c_ = (wave - 2) * 2;                                     \
            const u16* vr_ = Vh + k0_ + quad * 8 + (size_t)(l16 + 16 * c_) * Sn; \
            stage16(vr_,           b_ + 4096 + c_ * 1024);                     \
            stage16(vr_ + 16 * Sn, b_ + 4096 + c_ * 1024 + 1024);              \
        }                                                                      \
        const float* dr_ = Dh + k0_ + quad * 4;                                \
        const float* er_ = Eh + k0_ + quad * 4;                                \
        const int*   mr_ = Mh + k0_ + quad * 4;                                \
        char* w_ = b_ + 8192 + wave * 6144;                                    \
        stage16(dr_,       w_);                                                \
        stage16(dr_ + 16,  w_ + 1024);                                         \
        stage16(er_,       w_ + 2048);                                         \
        stage16(er_ + 16,  w_ + 3072);                                         \
        stage16(mr_,       w_ + 4096);                                         \
        stage16(mr_ + 16,  w_ + 5120);                                         \
    } while (0)

    f32x4 O0 = {0.f, 0.f, 0.f, 0.f}, O1 = O0, O2 = O0, O3 = O0;
    float m_run = -1e30f, l_run = 0.f;

    STAGE(sBuf, 0);
    __syncthreads();                    // tile 0 staged (all waves), table ready

    for (int t = 0; t < 8; t++) {
        char* cur = sBuf + (t & 1) * BUFSZ;
        if (t < 7) STAGE(sBuf + ((t & 1) ^ 1) * BUFSZ, t + 1);  // prefetch

        // identity readback: K/V shared, D/E/M from own wave region
        const char* ls = cur + lane * 16;
        const bf16x8 aK00 = *(const bf16x8*)(ls);
        const bf16x8 aK01 = *(const bf16x8*)(ls + 1024);
        const bf16x8 aK10 = *(const bf16x8*)(ls + 2048);
        const bf16x8 aK11 = *(const bf16x8*)(ls + 3072);
        const bf16x8 bV0  = *(const bf16x8*)(ls + 4096);
        const bf16x8 bV1  = *(const bf16x8*)(ls + 5120);
        const bf16x8 bV2  = *(const bf16x8*)(ls + 6144);
        const bf16x8 bV3  = *(const bf16x8*)(ls + 7168);
        const char* ld = cur + 8192 + wave * 6144 + lane * 16;
        const float4 Dv0  = *(const float4*)(ld);
        const float4 Dv1  = *(const float4*)(ld + 1024);
        const float4 Ev0  = *(const float4*)(ld + 2048);
        const float4 Ev1  = *(const float4*)(ld + 3072);
        const int4   Mv0  = *(const int4*)(ld + 4096);
        const int4   Mv1  = *(const int4*)(ld + 5120);

        f32x4 s0 = {0.f, 0.f, 0.f, 0.f}, s1 = s0;
        s0 = __builtin_amdgcn_mfma_f32_16x16x32_bf16(aK00, bQ0, s0, 0, 0, 0);
        s0 = __builtin_amdgcn_mfma_f32_16x16x32_bf16(aK01, bQ1, s0, 0, 0, 0);
        s1 = __builtin_amdgcn_mfma_f32_16x16x32_bf16(aK10, bQ0, s1, 0, 0, 0);
        s1 = __builtin_amdgcn_mfma_f32_16x16x32_bf16(aK11, bQ1, s1, 0, 0, 0);

        const float dv0[4] = {Dv0.x, Dv0.y, Dv0.z, Dv0.w};
        const float dv1[4] = {Dv1.x, Dv1.y, Dv1.z, Dv1.w};
        const float ev0[4] = {Ev0.x, Ev0.y, Ev0.z, Ev0.w};
        const float ev1[4] = {Ev1.x, Ev1.y, Ev1.z, Ev1.w};
        const int   mv0[4] = {Mv0.x, Mv0.y, Mv0.z, Mv0.w};
        const int   mv1[4] = {Mv1.x, Mv1.y, Mv1.z, Mv1.w};

        float sc0[4], sc1[4];
#pragma unroll
        for (int r = 0; r < 4; r++) {
            float v0 = s0[r] * scale + lerp_tab(sTab, dv0[r], invhD)
                                     + lerp_tab(sTab + TN, ev0[r], invhE);
            v0 = fminf(fmaxf(v0, -80.f), 80.f);
            sc0[r] = (mv0[r] == 0) ? -1e9f : v0;
            float v1 = s1[r] * scale + lerp_tab(sTab, dv1[r], invhD)
                                     + lerp_tab(sTab + TN, ev1[r], invhE);
            v1 = fminf(fmaxf(v1, -80.f), 80.f);
            sc1[r] = (mv1[r] == 0) ? -1e9f : v1;
        }

        // row max: local over 8 values, then across quads (2 shuffles)
        float mloc = fmaxf(fmaxf(fmaxf(sc0[0], sc0[1]), fmaxf(sc0[2], sc0[3])),
                           fmaxf(fmaxf(sc1[0], sc1[1]), fmaxf(sc1[2], sc1[3])));
        mloc = fmaxf(mloc, __shfl_xor(mloc, 16, 64));
        mloc = fmaxf(mloc, __shfl_xor(mloc, 32, 64));

        const float mn = fmaxf(m_run, mloc);
        const float al = __expf(m_run - mn);
        m_run = mn;

        float p0[4], p1[4], ll = 0.f;
#pragma unroll
        for (int r = 0; r < 4; r++) {
            p0[r] = __expf(sc0[r] - mn);
            p1[r] = __expf(sc1[r] - mn);
            ll += p0[r] + p1[r];
        }
        ll += __shfl_xor(ll, 16, 64);
        ll += __shfl_xor(ll, 32, 64);
        l_run = l_run * al + ll;

        // P A-fragment straight from registers (k-order matches permuted V)
        bf16x8 aP;
#pragma unroll
        for (int r = 0; r < 4; r++) {
            aP[r]     = (short)f2bf(p0[r]);
            aP[4 + r] = (short)f2bf(p1[r]);
        }

        // O rescale: alpha for row quad*4+r lives in lane (quad*4+r)
        const float a0 = __shfl(al, quad * 4 + 0, 64);
        const float a1 = __shfl(al, quad * 4 + 1, 64);
        const float a2 = __shfl(al, quad * 4 + 2, 64);
        const float a3 = __shfl(al, quad * 4 + 3, 64);
        O0[0] *= a0; O0[1] *= a1; O0[2] *= a2; O0[3] *= a3;
        O1[0] *= a0; O1[1] *= a1; O1[2] *= a2; O1[3] *= a3;
        O2[0] *= a0; O2[1] *= a1; O2[2] *= a2; O2[3] *= a3;
        O3[0] *= a0; O3[1] *= a1; O3[2] *= a2; O3[3] *= a3;

        O0 = __builtin_amdgcn_mfma_f32_16x16x32_bf16(aP, bV0, O0, 0, 0, 0);
        O1 = __builtin_amdgcn_mfma_f32_16x16x32_bf16(aP, bV1, O1, 0, 0, 0);
        O2 = __builtin_amdgcn_mfma_f32_16x16x32_bf16(aP, bV2, O2, 0, 0, 0);
        O3 = __builtin_amdgcn_mfma_f32_16x16x32_bf16(aP, bV3, O3, 0, 0, 0);

        // one barrier per tile: drains this wave's prefetch DMA (vmcnt(0)),
        // completes all waves' LDS reads of `cur` before it is re-staged
        __syncthreads();
    }
#undef STAGE

    // Per-wave partial (m, l, U) straight to workspace; no in-block combine.
    // O regs: [row = quad*4+r][d = vt*16 + l16], UNNORMALIZED.
    const int pb = (h * 64 + qb * 4 + wave) * KS + ks;
    float* up = Up + (size_t)pb * 1024;
#pragma unroll
    for (int r = 0; r < 4; r++) {
        const int row = quad * 4 + r;
        up[row * 64 +  0 + l16] = O0[r];
        up[row * 64 + 16 + l16] = O1[r];
        up[row * 64 + 32 + l16] = O2[r];
        up[row * 64 + 48 + l16] = O3[r];
    }
    if (lane < 16) {
        Mp[pb * 16 + lane] = m_run;
        Lp[pb * 16 + lane] = l_run;
    }
}

// ---------------------------------------------------------------------------
// Merge the KS=4 partials per q-row: M = max m_i; L = sum l_i e^{m_i-M};
// out = sum U_i e^{m_i-M} / L.  131072 threads, 16 threads/row.
// ---------------------------------------------------------------------------
__global__ __launch_bounds__(256) void combine_kernel(
    const float* __restrict__ Up, const float* __restrict__ Mp,
    const float* __restrict__ Lp, float* __restrict__ out)
{
    const int g  = blockIdx.x * 256 + threadIdx.x;
    const int r  = g >> 4;                 // global row 0..8191
    const int c4 = (g & 15) * 4;
    const int h  = r >> 10;
    const int s  = r & 1023;
    const int qt = s >> 4;                 // q-tile 0..63
    const int r16 = s & 15;
    const int pb0 = (h * 64 + qt) * KS;

    float m[KS], l[KS];
#pragma unroll
    for (int k = 0; k < KS; k++) {
        m[k] = Mp[(pb0 + k) * 16 + r16];
        l[k] = Lp[(pb0 + k) * 16 + r16];
    }
    float M = m[0];
#pragma unroll
    for (int k = 1; k < KS; k++) M = fmaxf(M, m[k]);
    float f[KS], L = 0.f;
#pragma unroll
    for (int k = 0; k < KS; k++) {
        f[k] = __expf(m[k] - M);
        L += l[k] * f[k];
    }
    const float inv = 1.0f / L;

    float acc[4] = {0.f, 0.f, 0.f, 0.f};
#pragma unroll
    for (int k = 0; k < KS; k++) {
        const float4 u = *(const float4*)(Up + (size_t)(pb0 + k) * 1024 + r16 * 64 + c4);
        acc[0] += u.x * f[k]; acc[1] += u.y * f[k];
        acc[2] += u.z * f[k]; acc[3] += u.w * f[k];
    }
    float4 ov = {acc[0] * inv, acc[1] * inv, acc[2] * inv, acc[3] * inv};
    *(float4*)(out + (size_t)r * Dn + c4) = ov;
}

// ---------------------------------------------------------------------------
extern "C" void kernel_launch(void* const* d_in, const int* in_sizes, int n_in,
                              void* d_out, int out_size, void* d_ws, size_t ws_size,
                              hipStream_t stream) {
    const float* Q    = (const float*)d_in[0];
    const float* K    = (const float*)d_in[1];
    const float* V    = (const float*)d_in[2];
    const float* Dm   = (const float*)d_in[3];
    const float* Em   = (const float*)d_in[4];
    const int*   Mask = (const int*)d_in[5];
    const float* muD  = (const float*)d_in[6];
    const float* sgD  = (const float*)d_in[7];
    const float* bD   = (const float*)d_in[8];
    const float* muE  = (const float*)d_in[9];
    const float* sgE  = (const float*)d_in[10];
    const float* bE   = (const float*)d_in[11];
    const float* W1   = (const float*)d_in[12];
    const float* b1   = (const float*)d_in[13];
    const float* W2   = (const float*)d_in[14];
    const float* b2   = (const float*)d_in[15];

    // ws: tab 16KB | Qb/Kb/VTi 1MB each | Up 8MB | Mp,Lp 128KB each (~11.4 MB)
    u32* tab = (u32*)d_ws;
    u16* Qb  = (u16*)((char*)d_ws + 2 * TN * 4);
    u16* Kb  = Qb + (size_t)Hn * Sn * Dn;
    u16* VTi = Kb + (size_t)Hn * Sn * Dn;
    float* Up = (float*)(VTi + (size_t)Hn * Sn * Dn);
    float* Mp = Up + (size_t)Hn * 64 * KS * 16 * 64;
    float* Lp = Mp + (size_t)Hn * 64 * KS * 16;

    const int prep_threads = 2 * TN + QK4 + VTN;           // 790528
    prep_kernel<<<prep_threads / 256, 256, 0, stream>>>(
        Q, K, V, muD, sgD, bD, muE, sgE, bE, W1, b1, W2, b2,
        tab, Qb, Kb, VTi);

    dim3 grid(Sn / 64, Hn, KS);
    attn_kernel<<<grid, 256, 0, stream>>>(Qb, Kb, VTi, Dm, Em, Mask, tab,
                                          Up, Mp, Lp);

    combine_kernel<<<(Hn * Sn * 16) / 256, 256, 0, stream>>>(Up, Mp, Lp,
                                                             (float*)d_out);
}